// Round 16
// baseline (131.102 us; speedup 1.0000x reference)
//
#include <hip/hip_runtime.h>
#include <math.h>

#define N_NODES 50000
#define NPAD    50048      // 391 * 128
#define F_IN    128
#define HID     256
#define NCLS    40
#define CAP     96         // per-node edge bucket capacity; P(deg>=96) ~ 1e-48
#define NB_FILL 2048       // 8 partitions x 256 slices

typedef __attribute__((ext_vector_type(8))) short bf16x8;
typedef __attribute__((ext_vector_type(4))) float f32x4;

__device__ inline ushort f2bf(float f) {
    uint u = __builtin_bit_cast(uint, f);
    u += 0x7FFF + ((u >> 16) & 1);          // round-to-nearest-even
    return (ushort)(u >> 16);
}
__device__ inline float bf2f(uint h16) {
    uint u = h16 << 16;
    return __builtin_bit_cast(float, u);
}
__device__ inline uchar f2fp8(float f) {
    return (uchar)(__builtin_amdgcn_cvt_pk_fp8_f32(f, f, 0u, false) & 0xff);
}

// ---------------- prep: zero fillpos + cast x->bf16 & fp8 + pack weights ----------------
// blocks [0,196): fillpos zero; [196,6446): cast_x (1.6M float4 -> bf16 + fp8);
// [6446,6782): weight pack. Streaming only, no scatter.

__global__ void prep_kernel(const float* __restrict__ x, ushort* __restrict__ xb,
                            uchar* __restrict__ xf8,
                            const float* __restrict__ W1l, const float* __restrict__ W1r,
                            const float* __restrict__ W2l, const float* __restrict__ W2r,
                            ushort* __restrict__ Wb1, ushort* __restrict__ Wb2,
                            int* __restrict__ fillpos) {
    int b = blockIdx.x, t = threadIdx.x;
    if (b < 196) {
        int i = b * 256 + t;
        if (i < N_NODES) fillpos[i] = 0;
    } else if (b < 6446) {
        int i = (b - 196) * 256 + t;     // < 1,600,000 exactly
        float4 v = *reinterpret_cast<const float4*>(x + (size_t)i * 4);
        ushort4 o;
        o.x = f2bf(v.x); o.y = f2bf(v.y); o.z = f2bf(v.z); o.w = f2bf(v.w);
        *reinterpret_cast<ushort4*>(xb + (size_t)i * 4) = o;
        uint w8 = __builtin_amdgcn_cvt_pk_fp8_f32(v.x, v.y, 0u, false);
        w8 = __builtin_amdgcn_cvt_pk_fp8_f32(v.z, v.w, w8, true);
        *reinterpret_cast<uint*>(xf8 + (size_t)i * 4) = w8;
    } else {
        int i = (b - 6446) * 256 + t;    // < 86016 exactly
        if (i < 65536) {
            int n = i >> 8, k = i & 255;
            float v = (k < 128) ? W1l[n * 128 + k] : W1r[n * 128 + (k - 128)];
            Wb1[i] = f2bf(v);
        } else {
            int j = i - 65536;           // < 20480
            int n = j >> 8, k = j & 255;
            float v = (n < 40) ? W2l[n * 256 + k] : W2r[(n - 40) * 256 + k];
            Wb2[j] = f2bf(v);
        }
    }
}

// ---------------- XCD-partitioned bucket fill ----------
// col2 is LAYER-MAJOR ushort: col2[p*N + n] = p-th in-neighbor of node n.
// dst/src are read with NONTEMPORAL loads so the edge stream does not evict the
// partition's sparsely-dirty col2 lines from its XCD L2 (the round-11..13
// partitioning failed because the stream polluted L2; writebacks stayed partial).

__global__ void fill_kernel(const int* __restrict__ src, const int* __restrict__ dst,
                            int* __restrict__ fillpos, ushort* __restrict__ col2, int E) {
    const int pid = blockIdx.x & 7;
    const int slice = blockIdx.x >> 3;                 // 0..255
    for (int i = slice * 256 + threadIdx.x; i < E; i += (NB_FILL >> 3) * 256) {
        int d = __builtin_nontemporal_load(dst + i);
        if (((uint)(d * 164) >> 20) == (uint)pid) {
            int p = atomicAdd(&fillpos[d], 1);
            int s = __builtin_nontemporal_load(src + i);
            if (p < CAP) col2[(size_t)p * N_NODES + d] = (ushort)s;
        }
    }
}

#define ACC8(A, V) \
    A[0] += bf2f(V.x & 0xffffu); A[1] += bf2f(V.x >> 16); \
    A[2] += bf2f(V.y & 0xffffu); A[3] += bf2f(V.y >> 16); \
    A[4] += bf2f(V.z & 0xffffu); A[5] += bf2f(V.z >> 16); \
    A[6] += bf2f(V.w & 0xffffu); A[7] += bf2f(V.w >> 16);

// fp8 gather accumulate: uint2 = 8 fp8 e4m3 values
#define ACC8F8(A, V) \
    A[0] += __builtin_amdgcn_cvt_f32_fp8(V.x, 0); A[1] += __builtin_amdgcn_cvt_f32_fp8(V.x, 1); \
    A[2] += __builtin_amdgcn_cvt_f32_fp8(V.x, 2); A[3] += __builtin_amdgcn_cvt_f32_fp8(V.x, 3); \
    A[4] += __builtin_amdgcn_cvt_f32_fp8(V.y, 0); A[5] += __builtin_amdgcn_cvt_f32_fp8(V.y, 1); \
    A[6] += __builtin_amdgcn_cvt_f32_fp8(V.y, 2); A[7] += __builtin_amdgcn_cvt_f32_fp8(V.y, 3);

// ---------------- mean aggregation layer 1 (fp8 gather: 128B/row) ----------
// 4 groups x 16 lanes x 8B; 2x guarded unroll (degree-appropriate: mean 12.8)

__global__ __launch_bounds__(256) void agg128_kernel(const uchar* __restrict__ xf8,
                                                     const int* __restrict__ fillpos,
                                                     const ushort* __restrict__ col2,
                                                     ushort* __restrict__ aggb) {
    int wid = threadIdx.x >> 6, l = threadIdx.x & 63;
    int n = blockIdx.x * 4 + wid;
    if (n >= N_NODES) return;
    int g = l >> 4, lr = l & 15;
    int deg = fillpos[n];
    if (deg > CAP) deg = CAP;
    float a[8] = {}, b[8] = {};
    int j = g;
    for (; j + 4 < deg; j += 8) {
        int c0 = col2[(size_t)j * N_NODES + n];
        int c1 = col2[(size_t)(j + 4) * N_NODES + n];
        uint2 v0 = *reinterpret_cast<const uint2*>(xf8 + (size_t)c0 * F_IN + lr * 8);
        uint2 v1 = *reinterpret_cast<const uint2*>(xf8 + (size_t)c1 * F_IN + lr * 8);
        ACC8F8(a, v0) ACC8F8(b, v1)
    }
    if (j < deg) {
        int c = col2[(size_t)j * N_NODES + n];
        uint2 v = *reinterpret_cast<const uint2*>(xf8 + (size_t)c * F_IN + lr * 8);
        ACC8F8(a, v)
    }
#pragma unroll
    for (int i = 0; i < 8; ++i) {
        a[i] += b[i];
        a[i] += __shfl_xor(a[i], 16);
        a[i] += __shfl_xor(a[i], 32);
    }
    if (g == 0) {
        float inv = 1.0f / (float)max(deg, 1);
        uint4 o;
        o.x = (uint)f2bf(a[0] * inv) | ((uint)f2bf(a[1] * inv) << 16);
        o.y = (uint)f2bf(a[2] * inv) | ((uint)f2bf(a[3] * inv) << 16);
        o.z = (uint)f2bf(a[4] * inv) | ((uint)f2bf(a[5] * inv) << 16);
        o.w = (uint)f2bf(a[6] * inv) | ((uint)f2bf(a[7] * inv) << 16);
        *reinterpret_cast<uint4*>(aggb + (size_t)n * F_IN + lr * 8) = o;
    }
}

// ---------------- fused GEMM1+GEMM2 ----------------
// Phase 1: h = relu([agg|x] @ Wb1.T + b1), Wb1 staged per-128-col half in 64KB LDS.
// Phase 2: h tile -> same LDS (bf16, swizzled; h never touches global).
// Phase 3: hWf8[row][0..39] = fp8(h @ W2l.T) (row padded to 64B = ONE cache line);
//          selfb[row][0..39] = bf16(h @ W2r.T + b2)  (self path keeps bf16 precision).

__global__ __launch_bounds__(256, 2) void gemm12_kernel(const ushort* __restrict__ aggb,
                                                        const ushort* __restrict__ xb,
                                                        const ushort* __restrict__ Wb1,
                                                        const float* __restrict__ b1,
                                                        const ushort* __restrict__ Wb2,
                                                        const float* __restrict__ b2,
                                                        uchar* __restrict__ hWf8,
                                                        ushort* __restrict__ selfb) {
    __shared__ __align__(16) char S[128 * 512];   // 64 KiB: B1-half staging, then h tile
    const int t = threadIdx.x, w = t >> 6, l = t & 63;
    const int bm = blockIdx.x * 128;
    const int lr = l & 15, lg = l >> 4;

    f32x4 acc[2][16] = {};
#pragma unroll
    for (int half = 0; half < 2; ++half) {
        for (int i = t; i < 128 * 32; i += 256) {
            int n = i >> 5, k8 = (i & 31) * 8;
            uint4 v = *reinterpret_cast<const uint4*>(Wb1 + (size_t)(half * 128 + n) * 256 + k8);
            *reinterpret_cast<uint4*>(S + ((n * 512 + k8 * 2) ^ ((n & 7) << 4))) = v;
        }
        __syncthreads();
#pragma unroll
        for (int kt = 0; kt < 8; ++kt) {
            const ushort* Ap = (kt < 4) ? aggb : xb;
            int kb = kt * 32 - ((kt < 4) ? 0 : 128) + lg * 8;
            bf16x8 a0 = *reinterpret_cast<const bf16x8*>(Ap + (size_t)(bm + w * 32 + lr) * F_IN + kb);
            bf16x8 a1 = *reinterpret_cast<const bf16x8*>(Ap + (size_t)(bm + w * 32 + 16 + lr) * F_IN + kb);
            int kbyte = kt * 64 + lg * 16;
#pragma unroll
            for (int j = 0; j < 8; ++j) {
                int nl = j * 16 + lr;
                bf16x8 b = *reinterpret_cast<const bf16x8*>(S + ((nl * 512 + kbyte) ^ ((nl & 7) << 4)));
                acc[0][half * 8 + j] = __builtin_amdgcn_mfma_f32_16x16x32_bf16(a0, b, acc[0][half * 8 + j], 0, 0, 0);
                acc[1][half * 8 + j] = __builtin_amdgcn_mfma_f32_16x16x32_bf16(a1, b, acc[1][half * 8 + j], 0, 0, 0);
            }
        }
        __syncthreads();
    }

    // write h tile (128 x 256 bf16) into S, swizzled, row stride 512B
#pragma unroll
    for (int j = 0; j < 16; ++j) {
        int c = j * 16 + lr;
        float bias = b1[c];
#pragma unroll
        for (int m = 0; m < 2; ++m) {
            int rowb = w * 32 + m * 16 + lg * 4;
#pragma unroll
            for (int r = 0; r < 4; ++r) {
                float v = fmaxf(acc[m][j][r] + bias, 0.f);
                int row = rowb + r;
                *reinterpret_cast<ushort*>(S + ((row * 512 + c * 2) ^ ((row & 7) << 4))) = f2bf(v);
            }
        }
    }
    __syncthreads();

    // GEMM2: A from LDS h, B = Wb2 from global (L2)
    f32x4 acc2[2][5] = {};
#pragma unroll
    for (int kt = 0; kt < 8; ++kt) {
        int kbyte = kt * 64 + lg * 16;
        int r0 = w * 32 + lr, r1 = r0 + 16;
        bf16x8 a0 = *reinterpret_cast<const bf16x8*>(S + ((r0 * 512 + kbyte) ^ ((r0 & 7) << 4)));
        bf16x8 a1 = *reinterpret_cast<const bf16x8*>(S + ((r1 * 512 + kbyte) ^ ((r1 & 7) << 4)));
#pragma unroll
        for (int j = 0; j < 5; ++j) {
            int nl = j * 16 + lr;
            bf16x8 b = *reinterpret_cast<const bf16x8*>(Wb2 + (size_t)nl * 256 + kt * 32 + lg * 8);
            acc2[0][j] = __builtin_amdgcn_mfma_f32_16x16x32_bf16(a0, b, acc2[0][j], 0, 0, 0);
            acc2[1][j] = __builtin_amdgcn_mfma_f32_16x16x32_bf16(a1, b, acc2[1][j], 0, 0, 0);
        }
    }
#pragma unroll
    for (int m = 0; m < 2; ++m) {
        int rbase = bm + w * 32 + m * 16 + lg * 4;
#pragma unroll
        for (int j = 0; j < 5; ++j) {
            int cfull = j * 16 + lr;
#pragma unroll
            for (int r = 0; r < 4; ++r) {
                int row = rbase + r;
                float v = acc2[m][j][r];
                if (cfull < 40) {
                    hWf8[(size_t)row * 64 + cfull] = f2fp8(v);        // 64B (1-line) rows
                } else {
                    int c = cfull - 40;
                    selfb[(size_t)row * 40 + c] = f2bf(v + b2[c]);
                }
            }
        }
    }
}

// ---------------- fused: out = log_softmax(self + mean_j hW_j) ----------------
// 8 groups of 8 lanes; lanes lr<5 load 8B fp8 each (40B of a 64B row = ONE line/edge);
// 2x guarded unroll (degree-appropriate)

__global__ __launch_bounds__(256) void agg40_lsm_kernel(const uchar* __restrict__ hWf8,
                                                        const ushort* __restrict__ selfb,
                                                        const int* __restrict__ fillpos,
                                                        const ushort* __restrict__ col2,
                                                        float* __restrict__ out) {
    int wid = threadIdx.x >> 6, l = threadIdx.x & 63;
    int n = blockIdx.x * 4 + wid;
    if (n >= N_NODES) return;
    int g = l >> 3, lr = l & 7;
    bool ld = lr < 5;
    bool act = (g == 0) && ld;
    int deg = fillpos[n];
    if (deg > CAP) deg = CAP;
    // self part issued early (hides under gather chain)
    uint4 sv = {};
    if (act) sv = *reinterpret_cast<const uint4*>(selfb + (size_t)n * 40 + lr * 8);
    float a[8] = {}, b[8] = {};
    int j = g;
    if (ld) {
        for (; j + 8 < deg; j += 16) {
            int c0 = col2[(size_t)j * N_NODES + n];
            int c1 = col2[(size_t)(j + 8) * N_NODES + n];
            uint2 v0 = *reinterpret_cast<const uint2*>(hWf8 + (size_t)c0 * 64 + lr * 8);
            uint2 v1 = *reinterpret_cast<const uint2*>(hWf8 + (size_t)c1 * 64 + lr * 8);
            ACC8F8(a, v0) ACC8F8(b, v1)
        }
        if (j < deg) {
            int c = col2[(size_t)j * N_NODES + n];
            uint2 v = *reinterpret_cast<const uint2*>(hWf8 + (size_t)c * 64 + lr * 8);
            ACC8F8(a, v)
        }
    }
#pragma unroll
    for (int i = 0; i < 8; ++i) {
        a[i] += b[i];
        a[i] += __shfl_xor(a[i], 8);
        a[i] += __shfl_xor(a[i], 16);
        a[i] += __shfl_xor(a[i], 32);
    }
    float inv = 1.0f / (float)max(deg, 1);
    float v[8];
    if (act) {
        v[0] = bf2f(sv.x & 0xffffu) + a[0] * inv; v[1] = bf2f(sv.x >> 16) + a[1] * inv;
        v[2] = bf2f(sv.y & 0xffffu) + a[2] * inv; v[3] = bf2f(sv.y >> 16) + a[3] * inv;
        v[4] = bf2f(sv.z & 0xffffu) + a[4] * inv; v[5] = bf2f(sv.z >> 16) + a[5] * inv;
        v[6] = bf2f(sv.w & 0xffffu) + a[6] * inv; v[7] = bf2f(sv.w >> 16) + a[7] * inv;
    } else {
#pragma unroll
        for (int i = 0; i < 8; ++i) v[i] = -INFINITY;
    }
    float m = v[0];
#pragma unroll
    for (int i = 1; i < 8; ++i) m = fmaxf(m, v[i]);
    m = fmaxf(m, __shfl_xor(m, 1));
    m = fmaxf(m, __shfl_xor(m, 2));
    m = fmaxf(m, __shfl_xor(m, 4));
    float ex = 0.f;
    if (act) {
#pragma unroll
        for (int i = 0; i < 8; ++i) ex += expf(v[i] - m);
    }
    ex += __shfl_xor(ex, 1);
    ex += __shfl_xor(ex, 2);
    ex += __shfl_xor(ex, 4);
    float ls = logf(ex);
    if (act) {
        float* ob = out + (size_t)n * NCLS + lr * 8;
        float4 o0, o1;
        o0.x = v[0] - m - ls; o0.y = v[1] - m - ls; o0.z = v[2] - m - ls; o0.w = v[3] - m - ls;
        o1.x = v[4] - m - ls; o1.y = v[5] - m - ls; o1.z = v[6] - m - ls; o1.w = v[7] - m - ls;
        *reinterpret_cast<float4*>(ob) = o0;
        *reinterpret_cast<float4*>(ob + 4) = o1;
    }
}

// ---------------- launch ----------------

static inline size_t align256(size_t x) { return (x + 255) & ~(size_t)255; }

extern "C" void kernel_launch(void* const* d_in, const int* in_sizes, int n_in,
                              void* d_out, int out_size, void* d_ws, size_t ws_size,
                              hipStream_t stream) {
    const float* x    = (const float*)d_in[0];
    const int*   ei   = (const int*)d_in[1];
    const float* W1l  = (const float*)d_in[2];
    const float* b1   = (const float*)d_in[3];
    const float* W1r  = (const float*)d_in[4];
    const float* W2l  = (const float*)d_in[5];
    const float* b2   = (const float*)d_in[6];
    const float* W2r  = (const float*)d_in[7];
    float* out = (float*)d_out;

    const int N = N_NODES;
    const int E = in_sizes[1] / 2;
    const int* srcArr = ei;
    const int* dstArr = ei + E;

    char* ws = (char*)d_ws;
    size_t off = 0;
    auto alloc = [&](size_t bytes) { size_t o = off; off = align256(off + bytes); return o; };
    int*    fillpos  = (int*)(ws + alloc((size_t)N * 4));
    ushort* col2     = (ushort*)(ws + alloc((size_t)CAP * N * 2));   // layer-major
    ushort* xb       = (ushort*)(ws + alloc((size_t)NPAD * F_IN * 2));
    uchar*  xf8      = (uchar*)(ws + alloc((size_t)NPAD * F_IN));
    ushort* aggb     = (ushort*)(ws + alloc((size_t)NPAD * F_IN * 2));
    uchar*  hWf8     = (uchar*)(ws + alloc((size_t)NPAD * 64));
    ushort* selfb    = (ushort*)(ws + alloc((size_t)NPAD * 40 * 2));
    ushort* Wb1      = (ushort*)(ws + alloc((size_t)256 * 256 * 2));
    ushort* Wb2      = (ushort*)(ws + alloc((size_t)80 * 256 * 2));
    (void)ws_size; (void)n_in; (void)out_size;

    // 1. prep: zero fillpos + cast (bf16 + fp8) + pack (streaming only)
    prep_kernel<<<6782, 256, 0, stream>>>(x, xb, xf8, W1l, W1r, W2l, W2r, Wb1, Wb2, fillpos);
    // 2. XCD-partitioned fill with nontemporal edge-stream loads
    fill_kernel<<<NB_FILL, 256, 0, stream>>>(srcArr, dstArr, fillpos, col2, E);
    // 3. layer-1 mean aggregation (fp8 gather)
    agg128_kernel<<<(N + 3) / 4, 256, 0, stream>>>(xf8, fillpos, col2, aggb);
    // 4. fused gemm1+gemm2 (h stays in LDS; aggregated part -> hWf8, self part -> selfb)
    gemm12_kernel<<<NPAD / 128, 256, 0, stream>>>(aggb, xb, Wb1, b1, Wb2, b2, hWf8, selfb);
    // 5. layer-2 aggregation + self + log_softmax
    agg40_lsm_kernel<<<(N + 3) / 4, 256, 0, stream>>>(hWf8, selfb, fillpos, col2, out);
}

// Round 17
// 118.199 us; speedup vs baseline: 1.1092x; 1.1092x over previous
//
#include <hip/hip_runtime.h>
#include <math.h>

#define N_NODES 50000
#define NPAD    50048      // 391 * 128
#define F_IN    128
#define HID     256
#define NCLS    40
#define CAP     96         // per-node edge bucket capacity; P(deg>=96) ~ 1e-48

// ---- two-pass binning params ----
#define NBIN      256
#define BIN_NODES 196      // 256*196 = 50176 >= 50000
#define MAGIC_BIN 85599u   // floor(d/196) = (d*85599)>>24, exact for d < ~89K
#define BSTRIDE   4096     // edges per bin region (mean 2500, 4096 = +32 sigma)
#define LCAP      3584     // LDS sort capacity per bin (+21 sigma)

typedef __attribute__((ext_vector_type(8))) short bf16x8;
typedef __attribute__((ext_vector_type(4))) float f32x4;

__device__ inline ushort f2bf(float f) {
    uint u = __builtin_bit_cast(uint, f);
    u += 0x7FFF + ((u >> 16) & 1);          // round-to-nearest-even
    return (ushort)(u >> 16);
}
__device__ inline float bf2f(uint h16) {
    uint u = h16 << 16;
    return __builtin_bit_cast(float, u);
}
__device__ inline uchar f2fp8(float f) {
    return (uchar)(__builtin_amdgcn_cvt_pk_fp8_f32(f, f, 0u, false) & 0xff);
}

// ---------------- prep: cast x->bf16 & fp8 + pack weights + zero bin counters ----------
// blocks [0,6250): cast_x (1.6M float4); [6250,6586): weight pack; 6586: zero bin_cnt.

__global__ void prep_kernel(const float* __restrict__ x, ushort* __restrict__ xb,
                            uchar* __restrict__ xf8,
                            const float* __restrict__ W1l, const float* __restrict__ W1r,
                            const float* __restrict__ W2l, const float* __restrict__ W2r,
                            ushort* __restrict__ Wb1, ushort* __restrict__ Wb2,
                            int* __restrict__ bin_cnt) {
    int b = blockIdx.x, t = threadIdx.x;
    if (b < 6250) {
        int i = b * 256 + t;             // < 1,600,000 exactly
        float4 v = *reinterpret_cast<const float4*>(x + (size_t)i * 4);
        ushort4 o;
        o.x = f2bf(v.x); o.y = f2bf(v.y); o.z = f2bf(v.z); o.w = f2bf(v.w);
        *reinterpret_cast<ushort4*>(xb + (size_t)i * 4) = o;
        uint w8 = __builtin_amdgcn_cvt_pk_fp8_f32(v.x, v.y, 0u, false);
        w8 = __builtin_amdgcn_cvt_pk_fp8_f32(v.z, v.w, w8, true);
        *reinterpret_cast<uint*>(xf8 + (size_t)i * 4) = w8;
    } else if (b < 6586) {
        int i = (b - 6250) * 256 + t;    // < 86016 exactly
        if (i < 65536) {
            int n = i >> 8, k = i & 255;
            float v = (k < 128) ? W1l[n * 128 + k] : W1r[n * 128 + (k - 128)];
            Wb1[i] = f2bf(v);
        } else {
            int j = i - 65536;           // < 20480
            int n = j >> 8, k = j & 255;
            float v = (n < 40) ? W2l[n * 256 + k] : W2r[(n - 40) * 256 + k];
            Wb2[j] = f2bf(v);
        }
    } else {
        bin_cnt[t] = 0;                  // NBIN == 256 == blockDim
    }
}

// ---------------- pass A: bin edges by 196-node dst range (LDS compaction) ----------
// Packs (dst<<16)|src into uint; per-block LDS sort by bin, then coalesced segment
// append to binbuf (global atomics only for per-bin reservations: 256/block).

__global__ __launch_bounds__(256) void bin_kernel(const int* __restrict__ src,
                                                  const int* __restrict__ dst,
                                                  int* __restrict__ bin_cnt,
                                                  uint* __restrict__ binbuf, int E) {
    __shared__ int cnt[NBIN], offs[NBIN], gbase[NBIN], segst[NBIN], tscan[NBIN];
    __shared__ uint stage[2048];
    const int t = threadIdx.x;
    const int base = blockIdx.x * 2048;
    cnt[t] = 0;
    __syncthreads();
    uint ed[8]; int pid[8];
#pragma unroll
    for (int i = 0; i < 8; ++i) {
        int idx = base + i * 256 + t;
        if (idx < E) {
            int d = dst[idx], s = src[idx];
            ed[i] = ((uint)d << 16) | (uint)s;
            pid[i] = (int)(((uint)d * MAGIC_BIN) >> 24);
            atomicAdd(&cnt[pid[i]], 1);
        } else pid[i] = -1;
    }
    __syncthreads();
    int myc = cnt[t];
    tscan[t] = myc;
    __syncthreads();
    for (int off = 1; off < 256; off <<= 1) {
        int u = (t >= off) ? tscan[t - off] : 0;
        __syncthreads();
        tscan[t] += u;
        __syncthreads();
    }
    segst[t] = tscan[t] - myc;
    offs[t]  = tscan[t] - myc;
    gbase[t] = atomicAdd(&bin_cnt[t], myc);
    __syncthreads();
#pragma unroll
    for (int i = 0; i < 8; ++i) {
        if (pid[i] >= 0) {
            int slot = atomicAdd(&offs[pid[i]], 1);
            stage[slot] = ed[i];
        }
    }
    __syncthreads();
    int total = min(2048, E - base);
    for (int i = t; i < total; i += 256) {
        uint pk = stage[i];
        int p = (int)(((pk >> 16) * MAGIC_BIN) >> 24);
        binbuf[(size_t)p * BSTRIDE + gbase[p] + (i - segst[p])] = pk;
    }
}

// ---------------- pass B: per-bin LDS counting sort -> dense col2 + fillpos ----------
// One block per bin (196 nodes). No global atomics; col2/fillpos written as dense
// coalesced stores (lines assembled fully on-chip -> no partial-line writebacks).
// col2 is LAYER-MAJOR ushort: col2[p*N + n] = p-th in-neighbor of node n.

__global__ __launch_bounds__(256) void fillb_kernel(const int* __restrict__ bin_cnt,
                                                    const uint* __restrict__ binbuf,
                                                    int* __restrict__ fillpos,
                                                    ushort* __restrict__ col2) {
    __shared__ int cnt[256], rowst[256], place[256], tscan[256];
    __shared__ ushort ssrc[LCAP];
    const int t = threadIdx.x;
    const int bin = blockIdx.x;
    const int nbase = bin * BIN_NODES;
    int nEb = bin_cnt[bin];
    if (nEb > LCAP) nEb = LCAP;
    const uint* eb = binbuf + (size_t)bin * BSTRIDE;
    cnt[t] = 0;
    __syncthreads();
    for (int i = t; i < nEb; i += 256) {
        int dl = (int)(eb[i] >> 16) - nbase;
        atomicAdd(&cnt[dl], 1);
    }
    __syncthreads();
    int myc = cnt[t];
    tscan[t] = myc;
    __syncthreads();
    for (int off = 1; off < 256; off <<= 1) {
        int u = (t >= off) ? tscan[t - off] : 0;
        __syncthreads();
        tscan[t] += u;
        __syncthreads();
    }
    rowst[t] = tscan[t] - myc;
    place[t] = tscan[t] - myc;
    __syncthreads();
    for (int i = t; i < nEb; i += 256) {
        uint pk = eb[i];
        int dl = (int)(pk >> 16) - nbase;
        int slot = atomicAdd(&place[dl], 1);
        ssrc[slot] = (ushort)(pk & 0xffffu);
    }
    __syncthreads();
    int n = nbase + t;
    if (t < BIN_NODES && n < N_NODES) {
        int rs = rowst[t];
        fillpos[n] = myc;
        int dmax = min(myc, CAP);
        for (int p = 0; p < dmax; ++p)
            col2[(size_t)p * N_NODES + n] = ssrc[rs + p];
    }
}

#define ACC8(A, V) \
    A[0] += bf2f(V.x & 0xffffu); A[1] += bf2f(V.x >> 16); \
    A[2] += bf2f(V.y & 0xffffu); A[3] += bf2f(V.y >> 16); \
    A[4] += bf2f(V.z & 0xffffu); A[5] += bf2f(V.z >> 16); \
    A[6] += bf2f(V.w & 0xffffu); A[7] += bf2f(V.w >> 16);

// fp8 gather accumulate: uint2 = 8 fp8 e4m3 values
#define ACC8F8(A, V) \
    A[0] += __builtin_amdgcn_cvt_f32_fp8(V.x, 0); A[1] += __builtin_amdgcn_cvt_f32_fp8(V.x, 1); \
    A[2] += __builtin_amdgcn_cvt_f32_fp8(V.x, 2); A[3] += __builtin_amdgcn_cvt_f32_fp8(V.x, 3); \
    A[4] += __builtin_amdgcn_cvt_f32_fp8(V.y, 0); A[5] += __builtin_amdgcn_cvt_f32_fp8(V.y, 1); \
    A[6] += __builtin_amdgcn_cvt_f32_fp8(V.y, 2); A[7] += __builtin_amdgcn_cvt_f32_fp8(V.y, 3);

// ---------------- mean aggregation layer 1 (fp8 gather: 128B/row) ----------
// 4 groups x 16 lanes x 8B; 2x guarded unroll (degree-appropriate: mean 12.8)

__global__ __launch_bounds__(256) void agg128_kernel(const uchar* __restrict__ xf8,
                                                     const int* __restrict__ fillpos,
                                                     const ushort* __restrict__ col2,
                                                     ushort* __restrict__ aggb) {
    int wid = threadIdx.x >> 6, l = threadIdx.x & 63;
    int n = blockIdx.x * 4 + wid;
    if (n >= N_NODES) return;
    int g = l >> 4, lr = l & 15;
    int deg = fillpos[n];
    if (deg > CAP) deg = CAP;
    float a[8] = {}, b[8] = {};
    int j = g;
    for (; j + 4 < deg; j += 8) {
        int c0 = col2[(size_t)j * N_NODES + n];
        int c1 = col2[(size_t)(j + 4) * N_NODES + n];
        uint2 v0 = *reinterpret_cast<const uint2*>(xf8 + (size_t)c0 * F_IN + lr * 8);
        uint2 v1 = *reinterpret_cast<const uint2*>(xf8 + (size_t)c1 * F_IN + lr * 8);
        ACC8F8(a, v0) ACC8F8(b, v1)
    }
    if (j < deg) {
        int c = col2[(size_t)j * N_NODES + n];
        uint2 v = *reinterpret_cast<const uint2*>(xf8 + (size_t)c * F_IN + lr * 8);
        ACC8F8(a, v)
    }
#pragma unroll
    for (int i = 0; i < 8; ++i) {
        a[i] += b[i];
        a[i] += __shfl_xor(a[i], 16);
        a[i] += __shfl_xor(a[i], 32);
    }
    if (g == 0) {
        float inv = 1.0f / (float)max(deg, 1);
        uint4 o;
        o.x = (uint)f2bf(a[0] * inv) | ((uint)f2bf(a[1] * inv) << 16);
        o.y = (uint)f2bf(a[2] * inv) | ((uint)f2bf(a[3] * inv) << 16);
        o.z = (uint)f2bf(a[4] * inv) | ((uint)f2bf(a[5] * inv) << 16);
        o.w = (uint)f2bf(a[6] * inv) | ((uint)f2bf(a[7] * inv) << 16);
        *reinterpret_cast<uint4*>(aggb + (size_t)n * F_IN + lr * 8) = o;
    }
}

// ---------------- fused GEMM1+GEMM2 ----------------
// Phase 1: h = relu([agg|x] @ Wb1.T + b1), Wb1 staged per-128-col half in 64KB LDS.
// Phase 2: h tile -> same LDS (bf16, swizzled; h never touches global).
// Phase 3: hWf8[row][0..39] = fp8(h @ W2l.T) (row padded to 64B = ONE cache line);
//          selfb[row][0..39] = bf16(h @ W2r.T + b2).

__global__ __launch_bounds__(256, 2) void gemm12_kernel(const ushort* __restrict__ aggb,
                                                        const ushort* __restrict__ xb,
                                                        const ushort* __restrict__ Wb1,
                                                        const float* __restrict__ b1,
                                                        const ushort* __restrict__ Wb2,
                                                        const float* __restrict__ b2,
                                                        uchar* __restrict__ hWf8,
                                                        ushort* __restrict__ selfb) {
    __shared__ __align__(16) char S[128 * 512];   // 64 KiB: B1-half staging, then h tile
    const int t = threadIdx.x, w = t >> 6, l = t & 63;
    const int bm = blockIdx.x * 128;
    const int lr = l & 15, lg = l >> 4;

    f32x4 acc[2][16] = {};
#pragma unroll
    for (int half = 0; half < 2; ++half) {
        for (int i = t; i < 128 * 32; i += 256) {
            int n = i >> 5, k8 = (i & 31) * 8;
            uint4 v = *reinterpret_cast<const uint4*>(Wb1 + (size_t)(half * 128 + n) * 256 + k8);
            *reinterpret_cast<uint4*>(S + ((n * 512 + k8 * 2) ^ ((n & 7) << 4))) = v;
        }
        __syncthreads();
#pragma unroll
        for (int kt = 0; kt < 8; ++kt) {
            const ushort* Ap = (kt < 4) ? aggb : xb;
            int kb = kt * 32 - ((kt < 4) ? 0 : 128) + lg * 8;
            bf16x8 a0 = *reinterpret_cast<const bf16x8*>(Ap + (size_t)(bm + w * 32 + lr) * F_IN + kb);
            bf16x8 a1 = *reinterpret_cast<const bf16x8*>(Ap + (size_t)(bm + w * 32 + 16 + lr) * F_IN + kb);
            int kbyte = kt * 64 + lg * 16;
#pragma unroll
            for (int j = 0; j < 8; ++j) {
                int nl = j * 16 + lr;
                bf16x8 b = *reinterpret_cast<const bf16x8*>(S + ((nl * 512 + kbyte) ^ ((nl & 7) << 4)));
                acc[0][half * 8 + j] = __builtin_amdgcn_mfma_f32_16x16x32_bf16(a0, b, acc[0][half * 8 + j], 0, 0, 0);
                acc[1][half * 8 + j] = __builtin_amdgcn_mfma_f32_16x16x32_bf16(a1, b, acc[1][half * 8 + j], 0, 0, 0);
            }
        }
        __syncthreads();
    }

    // write h tile (128 x 256 bf16) into S, swizzled, row stride 512B
#pragma unroll
    for (int j = 0; j < 16; ++j) {
        int c = j * 16 + lr;
        float bias = b1[c];
#pragma unroll
        for (int m = 0; m < 2; ++m) {
            int rowb = w * 32 + m * 16 + lg * 4;
#pragma unroll
            for (int r = 0; r < 4; ++r) {
                float v = fmaxf(acc[m][j][r] + bias, 0.f);
                int row = rowb + r;
                *reinterpret_cast<ushort*>(S + ((row * 512 + c * 2) ^ ((row & 7) << 4))) = f2bf(v);
            }
        }
    }
    __syncthreads();

    // GEMM2: A from LDS h, B = Wb2 from global (L2)
    f32x4 acc2[2][5] = {};
#pragma unroll
    for (int kt = 0; kt < 8; ++kt) {
        int kbyte = kt * 64 + lg * 16;
        int r0 = w * 32 + lr, r1 = r0 + 16;
        bf16x8 a0 = *reinterpret_cast<const bf16x8*>(S + ((r0 * 512 + kbyte) ^ ((r0 & 7) << 4)));
        bf16x8 a1 = *reinterpret_cast<const bf16x8*>(S + ((r1 * 512 + kbyte) ^ ((r1 & 7) << 4)));
#pragma unroll
        for (int j = 0; j < 5; ++j) {
            int nl = j * 16 + lr;
            bf16x8 b = *reinterpret_cast<const bf16x8*>(Wb2 + (size_t)nl * 256 + kt * 32 + lg * 8);
            acc2[0][j] = __builtin_amdgcn_mfma_f32_16x16x32_bf16(a0, b, acc2[0][j], 0, 0, 0);
            acc2[1][j] = __builtin_amdgcn_mfma_f32_16x16x32_bf16(a1, b, acc2[1][j], 0, 0, 0);
        }
    }
#pragma unroll
    for (int m = 0; m < 2; ++m) {
        int rbase = bm + w * 32 + m * 16 + lg * 4;
#pragma unroll
        for (int j = 0; j < 5; ++j) {
            int cfull = j * 16 + lr;
#pragma unroll
            for (int r = 0; r < 4; ++r) {
                int row = rbase + r;
                float v = acc2[m][j][r];
                if (cfull < 40) {
                    hWf8[(size_t)row * 64 + cfull] = f2fp8(v);        // 64B (1-line) rows
                } else {
                    int c = cfull - 40;
                    selfb[(size_t)row * 40 + c] = f2bf(v + b2[c]);
                }
            }
        }
    }
}

// ---------------- fused: out = log_softmax(self + mean_j hW_j) ----------------
// 8 groups of 8 lanes; lanes lr<5 load 8B fp8 each (40B of a 64B row = ONE line/edge);
// 2x guarded unroll (degree-appropriate)

__global__ __launch_bounds__(256) void agg40_lsm_kernel(const uchar* __restrict__ hWf8,
                                                        const ushort* __restrict__ selfb,
                                                        const int* __restrict__ fillpos,
                                                        const ushort* __restrict__ col2,
                                                        float* __restrict__ out) {
    int wid = threadIdx.x >> 6, l = threadIdx.x & 63;
    int n = blockIdx.x * 4 + wid;
    if (n >= N_NODES) return;
    int g = l >> 3, lr = l & 7;
    bool ld = lr < 5;
    bool act = (g == 0) && ld;
    int deg = fillpos[n];
    if (deg > CAP) deg = CAP;
    // self part issued early (hides under gather chain)
    uint4 sv = {};
    if (act) sv = *reinterpret_cast<const uint4*>(selfb + (size_t)n * 40 + lr * 8);
    float a[8] = {}, b[8] = {};
    int j = g;
    if (ld) {
        for (; j + 8 < deg; j += 16) {
            int c0 = col2[(size_t)j * N_NODES + n];
            int c1 = col2[(size_t)(j + 8) * N_NODES + n];
            uint2 v0 = *reinterpret_cast<const uint2*>(hWf8 + (size_t)c0 * 64 + lr * 8);
            uint2 v1 = *reinterpret_cast<const uint2*>(hWf8 + (size_t)c1 * 64 + lr * 8);
            ACC8F8(a, v0) ACC8F8(b, v1)
        }
        if (j < deg) {
            int c = col2[(size_t)j * N_NODES + n];
            uint2 v = *reinterpret_cast<const uint2*>(hWf8 + (size_t)c * 64 + lr * 8);
            ACC8F8(a, v)
        }
    }
#pragma unroll
    for (int i = 0; i < 8; ++i) {
        a[i] += b[i];
        a[i] += __shfl_xor(a[i], 8);
        a[i] += __shfl_xor(a[i], 16);
        a[i] += __shfl_xor(a[i], 32);
    }
    float inv = 1.0f / (float)max(deg, 1);
    float v[8];
    if (act) {
        v[0] = bf2f(sv.x & 0xffffu) + a[0] * inv; v[1] = bf2f(sv.x >> 16) + a[1] * inv;
        v[2] = bf2f(sv.y & 0xffffu) + a[2] * inv; v[3] = bf2f(sv.y >> 16) + a[3] * inv;
        v[4] = bf2f(sv.z & 0xffffu) + a[4] * inv; v[5] = bf2f(sv.z >> 16) + a[5] * inv;
        v[6] = bf2f(sv.w & 0xffffu) + a[6] * inv; v[7] = bf2f(sv.w >> 16) + a[7] * inv;
    } else {
#pragma unroll
        for (int i = 0; i < 8; ++i) v[i] = -INFINITY;
    }
    float m = v[0];
#pragma unroll
    for (int i = 1; i < 8; ++i) m = fmaxf(m, v[i]);
    m = fmaxf(m, __shfl_xor(m, 1));
    m = fmaxf(m, __shfl_xor(m, 2));
    m = fmaxf(m, __shfl_xor(m, 4));
    float ex = 0.f;
    if (act) {
#pragma unroll
        for (int i = 0; i < 8; ++i) ex += expf(v[i] - m);
    }
    ex += __shfl_xor(ex, 1);
    ex += __shfl_xor(ex, 2);
    ex += __shfl_xor(ex, 4);
    float ls = logf(ex);
    if (act) {
        float* ob = out + (size_t)n * NCLS + lr * 8;
        float4 o0, o1;
        o0.x = v[0] - m - ls; o0.y = v[1] - m - ls; o0.z = v[2] - m - ls; o0.w = v[3] - m - ls;
        o1.x = v[4] - m - ls; o1.y = v[5] - m - ls; o1.z = v[6] - m - ls; o1.w = v[7] - m - ls;
        *reinterpret_cast<float4*>(ob) = o0;
        *reinterpret_cast<float4*>(ob + 4) = o1;
    }
}

// ---------------- launch ----------------

static inline size_t align256(size_t x) { return (x + 255) & ~(size_t)255; }

extern "C" void kernel_launch(void* const* d_in, const int* in_sizes, int n_in,
                              void* d_out, int out_size, void* d_ws, size_t ws_size,
                              hipStream_t stream) {
    const float* x    = (const float*)d_in[0];
    const int*   ei   = (const int*)d_in[1];
    const float* W1l  = (const float*)d_in[2];
    const float* b1   = (const float*)d_in[3];
    const float* W1r  = (const float*)d_in[4];
    const float* W2l  = (const float*)d_in[5];
    const float* b2   = (const float*)d_in[6];
    const float* W2r  = (const float*)d_in[7];
    float* out = (float*)d_out;

    const int N = N_NODES;
    const int E = in_sizes[1] / 2;
    const int* srcArr = ei;
    const int* dstArr = ei + E;

    char* ws = (char*)d_ws;
    size_t off = 0;
    auto alloc = [&](size_t bytes) { size_t o = off; off = align256(off + bytes); return o; };
    int*    fillpos  = (int*)(ws + alloc((size_t)N * 4));
    int*    bin_cnt  = (int*)(ws + alloc((size_t)NBIN * 4));
    uint*   binbuf   = (uint*)(ws + alloc((size_t)NBIN * BSTRIDE * 4));   // 4 MB
    ushort* col2     = (ushort*)(ws + alloc((size_t)CAP * N * 2));        // layer-major
    ushort* xb       = (ushort*)(ws + alloc((size_t)NPAD * F_IN * 2));
    uchar*  xf8      = (uchar*)(ws + alloc((size_t)NPAD * F_IN));
    ushort* aggb     = (ushort*)(ws + alloc((size_t)NPAD * F_IN * 2));
    uchar*  hWf8     = (uchar*)(ws + alloc((size_t)NPAD * 64));
    ushort* selfb    = (ushort*)(ws + alloc((size_t)NPAD * 40 * 2));
    ushort* Wb1      = (ushort*)(ws + alloc((size_t)256 * 256 * 2));
    ushort* Wb2      = (ushort*)(ws + alloc((size_t)80 * 256 * 2));
    (void)ws_size; (void)n_in; (void)out_size;

    // 1. prep: cast (bf16 + fp8) + pack + zero bin counters
    prep_kernel<<<6587, 256, 0, stream>>>(x, xb, xf8, W1l, W1r, W2l, W2r, Wb1, Wb2, bin_cnt);
    // 2. pass A: bin edges into 256 node-range bins (LDS compaction, coalesced appends)
    bin_kernel<<<(E + 2047) / 2048, 256, 0, stream>>>(srcArr, dstArr, bin_cnt, binbuf, E);
    // 3. pass B: per-bin counting sort -> dense col2 + fillpos (no global atomics)
    fillb_kernel<<<NBIN, 256, 0, stream>>>(bin_cnt, binbuf, fillpos, col2);
    // 4. layer-1 mean aggregation (fp8 gather)
    agg128_kernel<<<(N + 3) / 4, 256, 0, stream>>>(xf8, fillpos, col2, aggb);
    // 5. fused gemm1+gemm2 (h stays in LDS; aggregated part -> hWf8, self part -> selfb)
    gemm12_kernel<<<NPAD / 128, 256, 0, stream>>>(aggb, xb, Wb1, b1, Wb2, b2, hWf8, selfb);
    // 6. layer-2 aggregation + self + log_softmax
    agg40_lsm_kernel<<<(N + 3) / 4, 256, 0, stream>>>(hWf8, selfb, fillpos, col2, out);
}

// Round 18
// 114.229 us; speedup vs baseline: 1.1477x; 1.0348x over previous
//
#include <hip/hip_runtime.h>
#include <math.h>

#define N_NODES 50000
#define NPAD    50048      // 391 * 128
#define F_IN    128
#define HID     256
#define NCLS    40
#define CAP     96         // per-node edge bucket capacity; P(deg>=96) ~ 1e-48

// ---- two-pass binning params ----
#define NBIN      256
#define BIN_NODES 196      // 256*196 = 50176 >= 50000
#define MAGIC_BIN 85599u   // floor(d/196) = (d*85599)>>24, exact for d < ~89K
#define BSTRIDE   4096     // edges per bin region (mean 2500, 4096 = +32 sigma)
#define LCAP      3584     // LDS sort capacity per bin (+21 sigma)

typedef __attribute__((ext_vector_type(8))) short bf16x8;
typedef __attribute__((ext_vector_type(4))) float f32x4;

__device__ inline ushort f2bf(float f) {
    uint u = __builtin_bit_cast(uint, f);
    u += 0x7FFF + ((u >> 16) & 1);          // round-to-nearest-even
    return (ushort)(u >> 16);
}
__device__ inline float bf2f(uint h16) {
    uint u = h16 << 16;
    return __builtin_bit_cast(float, u);
}
__device__ inline uchar f2fp8(float f) {
    return (uchar)(__builtin_amdgcn_cvt_pk_fp8_f32(f, f, 0u, false) & 0xff);
}

// ---------------- prep: cast x->bf16 & fp8 + pack weights + zero bin counters ----------
// blocks [0,6250): cast_x (1.6M float4); [6250,6586): weight pack; 6586: zero bin_cnt.

__global__ void prep_kernel(const float* __restrict__ x, ushort* __restrict__ xb,
                            uchar* __restrict__ xf8,
                            const float* __restrict__ W1l, const float* __restrict__ W1r,
                            const float* __restrict__ W2l, const float* __restrict__ W2r,
                            ushort* __restrict__ Wb1, ushort* __restrict__ Wb2,
                            int* __restrict__ bin_cnt) {
    int b = blockIdx.x, t = threadIdx.x;
    if (b < 6250) {
        int i = b * 256 + t;             // < 1,600,000 exactly
        float4 v = *reinterpret_cast<const float4*>(x + (size_t)i * 4);
        ushort4 o;
        o.x = f2bf(v.x); o.y = f2bf(v.y); o.z = f2bf(v.z); o.w = f2bf(v.w);
        *reinterpret_cast<ushort4*>(xb + (size_t)i * 4) = o;
        uint w8 = __builtin_amdgcn_cvt_pk_fp8_f32(v.x, v.y, 0u, false);
        w8 = __builtin_amdgcn_cvt_pk_fp8_f32(v.z, v.w, w8, true);
        *reinterpret_cast<uint*>(xf8 + (size_t)i * 4) = w8;
    } else if (b < 6586) {
        int i = (b - 6250) * 256 + t;    // < 86016 exactly
        if (i < 65536) {
            int n = i >> 8, k = i & 255;
            float v = (k < 128) ? W1l[n * 128 + k] : W1r[n * 128 + (k - 128)];
            Wb1[i] = f2bf(v);
        } else {
            int j = i - 65536;           // < 20480
            int n = j >> 8, k = j & 255;
            float v = (n < 40) ? W2l[n * 256 + k] : W2r[(n - 40) * 256 + k];
            Wb2[j] = f2bf(v);
        }
    } else {
        bin_cnt[t] = 0;                  // NBIN == 256 == blockDim
    }
}

// ---------------- pass A: bin edges by 196-node dst range (LDS compaction) ----------

__global__ __launch_bounds__(256) void bin_kernel(const int* __restrict__ src,
                                                  const int* __restrict__ dst,
                                                  int* __restrict__ bin_cnt,
                                                  uint* __restrict__ binbuf, int E) {
    __shared__ int cnt[NBIN], offs[NBIN], gbase[NBIN], segst[NBIN], tscan[NBIN];
    __shared__ uint stage[2048];
    const int t = threadIdx.x;
    const int base = blockIdx.x * 2048;
    cnt[t] = 0;
    __syncthreads();
    uint ed[8]; int pid[8];
#pragma unroll
    for (int i = 0; i < 8; ++i) {
        int idx = base + i * 256 + t;
        if (idx < E) {
            int d = dst[idx], s = src[idx];
            ed[i] = ((uint)d << 16) | (uint)s;
            pid[i] = (int)(((uint)d * MAGIC_BIN) >> 24);
            atomicAdd(&cnt[pid[i]], 1);
        } else pid[i] = -1;
    }
    __syncthreads();
    int myc = cnt[t];
    tscan[t] = myc;
    __syncthreads();
    for (int off = 1; off < 256; off <<= 1) {
        int u = (t >= off) ? tscan[t - off] : 0;
        __syncthreads();
        tscan[t] += u;
        __syncthreads();
    }
    segst[t] = tscan[t] - myc;
    offs[t]  = tscan[t] - myc;
    gbase[t] = atomicAdd(&bin_cnt[t], myc);
    __syncthreads();
#pragma unroll
    for (int i = 0; i < 8; ++i) {
        if (pid[i] >= 0) {
            int slot = atomicAdd(&offs[pid[i]], 1);
            stage[slot] = ed[i];
        }
    }
    __syncthreads();
    int total = min(2048, E - base);
    for (int i = t; i < total; i += 256) {
        uint pk = stage[i];
        int p = (int)(((pk >> 16) * MAGIC_BIN) >> 24);
        binbuf[(size_t)p * BSTRIDE + gbase[p] + (i - segst[p])] = pk;
    }
}

// ---------------- pass B: per-bin LDS counting sort -> dense col2 + fillpos ----------
// col2 is LAYER-MAJOR ushort: col2[p*N + n] = p-th in-neighbor of node n.

__global__ __launch_bounds__(256) void fillb_kernel(const int* __restrict__ bin_cnt,
                                                    const uint* __restrict__ binbuf,
                                                    int* __restrict__ fillpos,
                                                    ushort* __restrict__ col2) {
    __shared__ int cnt[256], rowst[256], place[256], tscan[256];
    __shared__ ushort ssrc[LCAP];
    const int t = threadIdx.x;
    const int bin = blockIdx.x;
    const int nbase = bin * BIN_NODES;
    int nEb = bin_cnt[bin];
    if (nEb > LCAP) nEb = LCAP;
    const uint* eb = binbuf + (size_t)bin * BSTRIDE;
    cnt[t] = 0;
    __syncthreads();
    for (int i = t; i < nEb; i += 256) {
        int dl = (int)(eb[i] >> 16) - nbase;
        atomicAdd(&cnt[dl], 1);
    }
    __syncthreads();
    int myc = cnt[t];
    tscan[t] = myc;
    __syncthreads();
    for (int off = 1; off < 256; off <<= 1) {
        int u = (t >= off) ? tscan[t - off] : 0;
        __syncthreads();
        tscan[t] += u;
        __syncthreads();
    }
    rowst[t] = tscan[t] - myc;
    place[t] = tscan[t] - myc;
    __syncthreads();
    for (int i = t; i < nEb; i += 256) {
        uint pk = eb[i];
        int dl = (int)(pk >> 16) - nbase;
        int slot = atomicAdd(&place[dl], 1);
        ssrc[slot] = (ushort)(pk & 0xffffu);
    }
    __syncthreads();
    int n = nbase + t;
    if (t < BIN_NODES && n < N_NODES) {
        int rs = rowst[t];
        fillpos[n] = myc;
        int dmax = min(myc, CAP);
        for (int p = 0; p < dmax; ++p)
            col2[(size_t)p * N_NODES + n] = ssrc[rs + p];
    }
}

#define ACC8(A, V) \
    A[0] += bf2f(V.x & 0xffffu); A[1] += bf2f(V.x >> 16); \
    A[2] += bf2f(V.y & 0xffffu); A[3] += bf2f(V.y >> 16); \
    A[4] += bf2f(V.z & 0xffffu); A[5] += bf2f(V.z >> 16); \
    A[6] += bf2f(V.w & 0xffffu); A[7] += bf2f(V.w >> 16);

// fp8 gather accumulate: uint2 = 8 fp8 e4m3 values
#define ACC8F8(A, V) \
    A[0] += __builtin_amdgcn_cvt_f32_fp8(V.x, 0); A[1] += __builtin_amdgcn_cvt_f32_fp8(V.x, 1); \
    A[2] += __builtin_amdgcn_cvt_f32_fp8(V.x, 2); A[3] += __builtin_amdgcn_cvt_f32_fp8(V.x, 3); \
    A[4] += __builtin_amdgcn_cvt_f32_fp8(V.y, 0); A[5] += __builtin_amdgcn_cvt_f32_fp8(V.y, 1); \
    A[6] += __builtin_amdgcn_cvt_f32_fp8(V.y, 2); A[7] += __builtin_amdgcn_cvt_f32_fp8(V.y, 3);

// uint4 = 16 fp8 e4m3 values
#define ACC16F8(A, V) \
    A[0]  += __builtin_amdgcn_cvt_f32_fp8(V.x, 0); A[1]  += __builtin_amdgcn_cvt_f32_fp8(V.x, 1); \
    A[2]  += __builtin_amdgcn_cvt_f32_fp8(V.x, 2); A[3]  += __builtin_amdgcn_cvt_f32_fp8(V.x, 3); \
    A[4]  += __builtin_amdgcn_cvt_f32_fp8(V.y, 0); A[5]  += __builtin_amdgcn_cvt_f32_fp8(V.y, 1); \
    A[6]  += __builtin_amdgcn_cvt_f32_fp8(V.y, 2); A[7]  += __builtin_amdgcn_cvt_f32_fp8(V.y, 3); \
    A[8]  += __builtin_amdgcn_cvt_f32_fp8(V.z, 0); A[9]  += __builtin_amdgcn_cvt_f32_fp8(V.z, 1); \
    A[10] += __builtin_amdgcn_cvt_f32_fp8(V.z, 2); A[11] += __builtin_amdgcn_cvt_f32_fp8(V.z, 3); \
    A[12] += __builtin_amdgcn_cvt_f32_fp8(V.w, 0); A[13] += __builtin_amdgcn_cvt_f32_fp8(V.w, 1); \
    A[14] += __builtin_amdgcn_cvt_f32_fp8(V.w, 2); A[15] += __builtin_amdgcn_cvt_f32_fp8(V.w, 3);

// ---------------- mean aggregation layer 1 ----------
// ONE NODE PER 8-LANE GROUP (8 nodes/wave, 32/block): lane owns 16B of the 128B
// fp8 row -> no cross-lane reduce, no idle lanes. 4x unrolled edge walk (fires
// deg>=4; mean 12.8 -> ~3 full iters) = 4 gathers in flight per group, 32/wave.

__global__ __launch_bounds__(256) void agg128_kernel(const uchar* __restrict__ xf8,
                                                     const int* __restrict__ fillpos,
                                                     const ushort* __restrict__ col2,
                                                     ushort* __restrict__ aggb) {
    const int t = threadIdx.x;
    const int n = blockIdx.x * 32 + (t >> 3);
    const int lr = t & 7;
    if (n >= N_NODES) return;
    int deg = fillpos[n];
    if (deg > CAP) deg = CAP;
    float a[16] = {}, b[16] = {};
    int j = 0;
    for (; j + 3 < deg; j += 4) {
        int c0 = col2[(size_t)j * N_NODES + n];
        int c1 = col2[(size_t)(j + 1) * N_NODES + n];
        int c2 = col2[(size_t)(j + 2) * N_NODES + n];
        int c3 = col2[(size_t)(j + 3) * N_NODES + n];
        uint4 v0 = *reinterpret_cast<const uint4*>(xf8 + (size_t)c0 * F_IN + lr * 16);
        uint4 v1 = *reinterpret_cast<const uint4*>(xf8 + (size_t)c1 * F_IN + lr * 16);
        uint4 v2 = *reinterpret_cast<const uint4*>(xf8 + (size_t)c2 * F_IN + lr * 16);
        uint4 v3 = *reinterpret_cast<const uint4*>(xf8 + (size_t)c3 * F_IN + lr * 16);
        ACC16F8(a, v0) ACC16F8(b, v1) ACC16F8(a, v2) ACC16F8(b, v3)
    }
    for (; j < deg; ++j) {
        int c = col2[(size_t)j * N_NODES + n];
        uint4 v = *reinterpret_cast<const uint4*>(xf8 + (size_t)c * F_IN + lr * 16);
        ACC16F8(a, v)
    }
    float inv = 1.0f / (float)max(deg, 1);
    uint4 o0, o1;
    o0.x = (uint)f2bf((a[0]  + b[0])  * inv) | ((uint)f2bf((a[1]  + b[1])  * inv) << 16);
    o0.y = (uint)f2bf((a[2]  + b[2])  * inv) | ((uint)f2bf((a[3]  + b[3])  * inv) << 16);
    o0.z = (uint)f2bf((a[4]  + b[4])  * inv) | ((uint)f2bf((a[5]  + b[5])  * inv) << 16);
    o0.w = (uint)f2bf((a[6]  + b[6])  * inv) | ((uint)f2bf((a[7]  + b[7])  * inv) << 16);
    o1.x = (uint)f2bf((a[8]  + b[8])  * inv) | ((uint)f2bf((a[9]  + b[9])  * inv) << 16);
    o1.y = (uint)f2bf((a[10] + b[10]) * inv) | ((uint)f2bf((a[11] + b[11]) * inv) << 16);
    o1.z = (uint)f2bf((a[12] + b[12]) * inv) | ((uint)f2bf((a[13] + b[13]) * inv) << 16);
    o1.w = (uint)f2bf((a[14] + b[14]) * inv) | ((uint)f2bf((a[15] + b[15]) * inv) << 16);
    *reinterpret_cast<uint4*>(aggb + (size_t)n * F_IN + lr * 16) = o0;
    *reinterpret_cast<uint4*>(aggb + (size_t)n * F_IN + lr * 16 + 8) = o1;
}

// ---------------- fused GEMM1+GEMM2 ----------------

__global__ __launch_bounds__(256, 2) void gemm12_kernel(const ushort* __restrict__ aggb,
                                                        const ushort* __restrict__ xb,
                                                        const ushort* __restrict__ Wb1,
                                                        const float* __restrict__ b1,
                                                        const ushort* __restrict__ Wb2,
                                                        const float* __restrict__ b2,
                                                        uchar* __restrict__ hWf8,
                                                        ushort* __restrict__ selfb) {
    __shared__ __align__(16) char S[128 * 512];   // 64 KiB: B1-half staging, then h tile
    const int t = threadIdx.x, w = t >> 6, l = t & 63;
    const int bm = blockIdx.x * 128;
    const int lr = l & 15, lg = l >> 4;

    f32x4 acc[2][16] = {};
#pragma unroll
    for (int half = 0; half < 2; ++half) {
        for (int i = t; i < 128 * 32; i += 256) {
            int n = i >> 5, k8 = (i & 31) * 8;
            uint4 v = *reinterpret_cast<const uint4*>(Wb1 + (size_t)(half * 128 + n) * 256 + k8);
            *reinterpret_cast<uint4*>(S + ((n * 512 + k8 * 2) ^ ((n & 7) << 4))) = v;
        }
        __syncthreads();
#pragma unroll
        for (int kt = 0; kt < 8; ++kt) {
            const ushort* Ap = (kt < 4) ? aggb : xb;
            int kb = kt * 32 - ((kt < 4) ? 0 : 128) + lg * 8;
            bf16x8 a0 = *reinterpret_cast<const bf16x8*>(Ap + (size_t)(bm + w * 32 + lr) * F_IN + kb);
            bf16x8 a1 = *reinterpret_cast<const bf16x8*>(Ap + (size_t)(bm + w * 32 + 16 + lr) * F_IN + kb);
            int kbyte = kt * 64 + lg * 16;
#pragma unroll
            for (int j = 0; j < 8; ++j) {
                int nl = j * 16 + lr;
                bf16x8 b = *reinterpret_cast<const bf16x8*>(S + ((nl * 512 + kbyte) ^ ((nl & 7) << 4)));
                acc[0][half * 8 + j] = __builtin_amdgcn_mfma_f32_16x16x32_bf16(a0, b, acc[0][half * 8 + j], 0, 0, 0);
                acc[1][half * 8 + j] = __builtin_amdgcn_mfma_f32_16x16x32_bf16(a1, b, acc[1][half * 8 + j], 0, 0, 0);
            }
        }
        __syncthreads();
    }

    // write h tile (128 x 256 bf16) into S, swizzled, row stride 512B
#pragma unroll
    for (int j = 0; j < 16; ++j) {
        int c = j * 16 + lr;
        float bias = b1[c];
#pragma unroll
        for (int m = 0; m < 2; ++m) {
            int rowb = w * 32 + m * 16 + lg * 4;
#pragma unroll
            for (int r = 0; r < 4; ++r) {
                float v = fmaxf(acc[m][j][r] + bias, 0.f);
                int row = rowb + r;
                *reinterpret_cast<ushort*>(S + ((row * 512 + c * 2) ^ ((row & 7) << 4))) = f2bf(v);
            }
        }
    }
    __syncthreads();

    // GEMM2: A from LDS h, B = Wb2 from global (L2)
    f32x4 acc2[2][5] = {};
#pragma unroll
    for (int kt = 0; kt < 8; ++kt) {
        int kbyte = kt * 64 + lg * 16;
        int r0 = w * 32 + lr, r1 = r0 + 16;
        bf16x8 a0 = *reinterpret_cast<const bf16x8*>(S + ((r0 * 512 + kbyte) ^ ((r0 & 7) << 4)));
        bf16x8 a1 = *reinterpret_cast<const bf16x8*>(S + ((r1 * 512 + kbyte) ^ ((r1 & 7) << 4)));
#pragma unroll
        for (int j = 0; j < 5; ++j) {
            int nl = j * 16 + lr;
            bf16x8 b = *reinterpret_cast<const bf16x8*>(Wb2 + (size_t)nl * 256 + kt * 32 + lg * 8);
            acc2[0][j] = __builtin_amdgcn_mfma_f32_16x16x32_bf16(a0, b, acc2[0][j], 0, 0, 0);
            acc2[1][j] = __builtin_amdgcn_mfma_f32_16x16x32_bf16(a1, b, acc2[1][j], 0, 0, 0);
        }
    }
#pragma unroll
    for (int m = 0; m < 2; ++m) {
        int rbase = bm + w * 32 + m * 16 + lg * 4;
#pragma unroll
        for (int j = 0; j < 5; ++j) {
            int cfull = j * 16 + lr;
#pragma unroll
            for (int r = 0; r < 4; ++r) {
                int row = rbase + r;
                float v = acc2[m][j][r];
                if (cfull < 40) {
                    hWf8[(size_t)row * 64 + cfull] = f2fp8(v);        // 64B (1-line) rows
                } else {
                    int c = cfull - 40;
                    selfb[(size_t)row * 40 + c] = f2bf(v + b2[c]);
                }
            }
        }
    }
}

// ---------------- fused: out = log_softmax(self + mean_j hW_j) ----------------

__global__ __launch_bounds__(256) void agg40_lsm_kernel(const uchar* __restrict__ hWf8,
                                                        const ushort* __restrict__ selfb,
                                                        const int* __restrict__ fillpos,
                                                        const ushort* __restrict__ col2,
                                                        float* __restrict__ out) {
    int wid = threadIdx.x >> 6, l = threadIdx.x & 63;
    int n = blockIdx.x * 4 + wid;
    if (n >= N_NODES) return;
    int g = l >> 3, lr = l & 7;
    bool ld = lr < 5;
    bool act = (g == 0) && ld;
    int deg = fillpos[n];
    if (deg > CAP) deg = CAP;
    // self part issued early (hides under gather chain)
    uint4 sv = {};
    if (act) sv = *reinterpret_cast<const uint4*>(selfb + (size_t)n * 40 + lr * 8);
    float a[8] = {}, b[8] = {};
    int j = g;
    if (ld) {
        for (; j + 8 < deg; j += 16) {
            int c0 = col2[(size_t)j * N_NODES + n];
            int c1 = col2[(size_t)(j + 8) * N_NODES + n];
            uint2 v0 = *reinterpret_cast<const uint2*>(hWf8 + (size_t)c0 * 64 + lr * 8);
            uint2 v1 = *reinterpret_cast<const uint2*>(hWf8 + (size_t)c1 * 64 + lr * 8);
            ACC8F8(a, v0) ACC8F8(b, v1)
        }
        if (j < deg) {
            int c = col2[(size_t)j * N_NODES + n];
            uint2 v = *reinterpret_cast<const uint2*>(hWf8 + (size_t)c * 64 + lr * 8);
            ACC8F8(a, v)
        }
    }
#pragma unroll
    for (int i = 0; i < 8; ++i) {
        a[i] += b[i];
        a[i] += __shfl_xor(a[i], 8);
        a[i] += __shfl_xor(a[i], 16);
        a[i] += __shfl_xor(a[i], 32);
    }
    float inv = 1.0f / (float)max(deg, 1);
    float v[8];
    if (act) {
        v[0] = bf2f(sv.x & 0xffffu) + a[0] * inv; v[1] = bf2f(sv.x >> 16) + a[1] * inv;
        v[2] = bf2f(sv.y & 0xffffu) + a[2] * inv; v[3] = bf2f(sv.y >> 16) + a[3] * inv;
        v[4] = bf2f(sv.z & 0xffffu) + a[4] * inv; v[5] = bf2f(sv.z >> 16) + a[5] * inv;
        v[6] = bf2f(sv.w & 0xffffu) + a[6] * inv; v[7] = bf2f(sv.w >> 16) + a[7] * inv;
    } else {
#pragma unroll
        for (int i = 0; i < 8; ++i) v[i] = -INFINITY;
    }
    float m = v[0];
#pragma unroll
    for (int i = 1; i < 8; ++i) m = fmaxf(m, v[i]);
    m = fmaxf(m, __shfl_xor(m, 1));
    m = fmaxf(m, __shfl_xor(m, 2));
    m = fmaxf(m, __shfl_xor(m, 4));
    float ex = 0.f;
    if (act) {
#pragma unroll
        for (int i = 0; i < 8; ++i) ex += expf(v[i] - m);
    }
    ex += __shfl_xor(ex, 1);
    ex += __shfl_xor(ex, 2);
    ex += __shfl_xor(ex, 4);
    float ls = logf(ex);
    if (act) {
        float* ob = out + (size_t)n * NCLS + lr * 8;
        float4 o0, o1;
        o0.x = v[0] - m - ls; o0.y = v[1] - m - ls; o0.z = v[2] - m - ls; o0.w = v[3] - m - ls;
        o1.x = v[4] - m - ls; o1.y = v[5] - m - ls; o1.z = v[6] - m - ls; o1.w = v[7] - m - ls;
        *reinterpret_cast<float4*>(ob) = o0;
        *reinterpret_cast<float4*>(ob + 4) = o1;
    }
}

// ---------------- launch ----------------

static inline size_t align256(size_t x) { return (x + 255) & ~(size_t)255; }

extern "C" void kernel_launch(void* const* d_in, const int* in_sizes, int n_in,
                              void* d_out, int out_size, void* d_ws, size_t ws_size,
                              hipStream_t stream) {
    const float* x    = (const float*)d_in[0];
    const int*   ei   = (const int*)d_in[1];
    const float* W1l  = (const float*)d_in[2];
    const float* b1   = (const float*)d_in[3];
    const float* W1r  = (const float*)d_in[4];
    const float* W2l  = (const float*)d_in[5];
    const float* b2   = (const float*)d_in[6];
    const float* W2r  = (const float*)d_in[7];
    float* out = (float*)d_out;

    const int N = N_NODES;
    const int E = in_sizes[1] / 2;
    const int* srcArr = ei;
    const int* dstArr = ei + E;

    char* ws = (char*)d_ws;
    size_t off = 0;
    auto alloc = [&](size_t bytes) { size_t o = off; off = align256(off + bytes); return o; };
    int*    fillpos  = (int*)(ws + alloc((size_t)N * 4));
    int*    bin_cnt  = (int*)(ws + alloc((size_t)NBIN * 4));
    uint*   binbuf   = (uint*)(ws + alloc((size_t)NBIN * BSTRIDE * 4));   // 4 MB
    ushort* col2     = (ushort*)(ws + alloc((size_t)CAP * N * 2));        // layer-major
    ushort* xb       = (ushort*)(ws + alloc((size_t)NPAD * F_IN * 2));
    uchar*  xf8      = (uchar*)(ws + alloc((size_t)NPAD * F_IN));
    ushort* aggb     = (ushort*)(ws + alloc((size_t)NPAD * F_IN * 2));
    uchar*  hWf8     = (uchar*)(ws + alloc((size_t)NPAD * 64));
    ushort* selfb    = (ushort*)(ws + alloc((size_t)NPAD * 40 * 2));
    ushort* Wb1      = (ushort*)(ws + alloc((size_t)256 * 256 * 2));
    ushort* Wb2      = (ushort*)(ws + alloc((size_t)80 * 256 * 2));
    (void)ws_size; (void)n_in; (void)out_size;

    // 1. prep: cast (bf16 + fp8) + pack + zero bin counters
    prep_kernel<<<6587, 256, 0, stream>>>(x, xb, xf8, W1l, W1r, W2l, W2r, Wb1, Wb2, bin_cnt);
    // 2. pass A: bin edges into 256 node-range bins
    bin_kernel<<<(E + 2047) / 2048, 256, 0, stream>>>(srcArr, dstArr, bin_cnt, binbuf, E);
    // 3. pass B: per-bin counting sort -> dense col2 + fillpos
    fillb_kernel<<<NBIN, 256, 0, stream>>>(bin_cnt, binbuf, fillpos, col2);
    // 4. layer-1 mean aggregation (node-per-8-lane-group, 4-deep MLP)
    agg128_kernel<<<(N + 31) / 32, 256, 0, stream>>>(xf8, fillpos, col2, aggb);
    // 5. fused gemm1+gemm2 (h stays in LDS)
    gemm12_kernel<<<NPAD / 128, 256, 0, stream>>>(aggb, xb, Wb1, b1, Wb2, b2, hWf8, selfb);
    // 6. layer-2 aggregation + self + log_softmax
    agg40_lsm_kernel<<<(N + 3) / 4, 256, 0, stream>>>(hWf8, selfb, fillpos, col2, out);
}

// Round 19
// 108.601 us; speedup vs baseline: 1.2072x; 1.0518x over previous
//
#include <hip/hip_runtime.h>
#include <math.h>

#define N_NODES 50000
#define NPAD    50048      // 391 * 128
#define F_IN    128
#define HID     256
#define NCLS    40
#define CAP     96         // per-node edge bucket capacity; P(deg>=96) ~ 1e-48

// ---- two-pass binning params ----
#define NBIN      256
#define BIN_NODES 196      // 256*196 = 50176 >= 50000
#define MAGIC_BIN 85599u   // floor(d/196) = (d*85599)>>24, exact for d < ~89K
#define BSTRIDE   4096     // edges per bin region (mean 2500, 4096 = +32 sigma)
#define LCAP      3584     // LDS sort capacity per bin (+21 sigma)

typedef __attribute__((ext_vector_type(8))) short bf16x8;
typedef __attribute__((ext_vector_type(4))) float f32x4;

__device__ inline ushort f2bf(float f) {
    uint u = __builtin_bit_cast(uint, f);
    u += 0x7FFF + ((u >> 16) & 1);          // round-to-nearest-even
    return (ushort)(u >> 16);
}
__device__ inline float bf2f(uint h16) {
    uint u = h16 << 16;
    return __builtin_bit_cast(float, u);
}
__device__ inline uchar f2fp8(float f) {
    return (uchar)(__builtin_amdgcn_cvt_pk_fp8_f32(f, f, 0u, false) & 0xff);
}

// ---------------- prep: cast x->bf16 & fp8 + pack weights + zero bin counters ----------

__global__ void prep_kernel(const float* __restrict__ x, ushort* __restrict__ xb,
                            uchar* __restrict__ xf8,
                            const float* __restrict__ W1l, const float* __restrict__ W1r,
                            const float* __restrict__ W2l, const float* __restrict__ W2r,
                            ushort* __restrict__ Wb1, ushort* __restrict__ Wb2,
                            int* __restrict__ bin_cnt) {
    int b = blockIdx.x, t = threadIdx.x;
    if (b < 6250) {
        int i = b * 256 + t;             // < 1,600,000 exactly
        float4 v = *reinterpret_cast<const float4*>(x + (size_t)i * 4);
        ushort4 o;
        o.x = f2bf(v.x); o.y = f2bf(v.y); o.z = f2bf(v.z); o.w = f2bf(v.w);
        *reinterpret_cast<ushort4*>(xb + (size_t)i * 4) = o;
        uint w8 = __builtin_amdgcn_cvt_pk_fp8_f32(v.x, v.y, 0u, false);
        w8 = __builtin_amdgcn_cvt_pk_fp8_f32(v.z, v.w, w8, true);
        *reinterpret_cast<uint*>(xf8 + (size_t)i * 4) = w8;
    } else if (b < 6586) {
        int i = (b - 6250) * 256 + t;    // < 86016 exactly
        if (i < 65536) {
            int n = i >> 8, k = i & 255;
            float v = (k < 128) ? W1l[n * 128 + k] : W1r[n * 128 + (k - 128)];
            Wb1[i] = f2bf(v);
        } else {
            int j = i - 65536;           // < 20480
            int n = j >> 8, k = j & 255;
            float v = (n < 40) ? W2l[n * 256 + k] : W2r[(n - 40) * 256 + k];
            Wb2[j] = f2bf(v);
        }
    } else {
        bin_cnt[t] = 0;                  // NBIN == 256 == blockDim
    }
}

// ---------------- pass A: bin edges by 196-node dst range (LDS compaction) ----------

__global__ __launch_bounds__(256) void bin_kernel(const int* __restrict__ src,
                                                  const int* __restrict__ dst,
                                                  int* __restrict__ bin_cnt,
                                                  uint* __restrict__ binbuf, int E) {
    __shared__ int cnt[NBIN], offs[NBIN], gbase[NBIN], segst[NBIN], tscan[NBIN];
    __shared__ uint stage[2048];
    const int t = threadIdx.x;
    const int base = blockIdx.x * 2048;
    cnt[t] = 0;
    __syncthreads();
    uint ed[8]; int pid[8];
#pragma unroll
    for (int i = 0; i < 8; ++i) {
        int idx = base + i * 256 + t;
        if (idx < E) {
            int d = dst[idx], s = src[idx];
            ed[i] = ((uint)d << 16) | (uint)s;
            pid[i] = (int)(((uint)d * MAGIC_BIN) >> 24);
            atomicAdd(&cnt[pid[i]], 1);
        } else pid[i] = -1;
    }
    __syncthreads();
    int myc = cnt[t];
    tscan[t] = myc;
    __syncthreads();
    for (int off = 1; off < 256; off <<= 1) {
        int u = (t >= off) ? tscan[t - off] : 0;
        __syncthreads();
        tscan[t] += u;
        __syncthreads();
    }
    segst[t] = tscan[t] - myc;
    offs[t]  = tscan[t] - myc;
    gbase[t] = atomicAdd(&bin_cnt[t], myc);
    __syncthreads();
#pragma unroll
    for (int i = 0; i < 8; ++i) {
        if (pid[i] >= 0) {
            int slot = atomicAdd(&offs[pid[i]], 1);
            stage[slot] = ed[i];
        }
    }
    __syncthreads();
    int total = min(2048, E - base);
    for (int i = t; i < total; i += 256) {
        uint pk = stage[i];
        int p = (int)(((pk >> 16) * MAGIC_BIN) >> 24);
        binbuf[(size_t)p * BSTRIDE + gbase[p] + (i - segst[p])] = pk;
    }
}

// ---------------- pass B: per-bin LDS counting sort -> dense col2 + fillpos ----------
// col2 is LAYER-MAJOR ushort: col2[p*N + n] = p-th in-neighbor of node n.

__global__ __launch_bounds__(256) void fillb_kernel(const int* __restrict__ bin_cnt,
                                                    const uint* __restrict__ binbuf,
                                                    int* __restrict__ fillpos,
                                                    ushort* __restrict__ col2) {
    __shared__ int cnt[256], rowst[256], place[256], tscan[256];
    __shared__ ushort ssrc[LCAP];
    const int t = threadIdx.x;
    const int bin = blockIdx.x;
    const int nbase = bin * BIN_NODES;
    int nEb = bin_cnt[bin];
    if (nEb > LCAP) nEb = LCAP;
    const uint* eb = binbuf + (size_t)bin * BSTRIDE;
    cnt[t] = 0;
    __syncthreads();
    for (int i = t; i < nEb; i += 256) {
        int dl = (int)(eb[i] >> 16) - nbase;
        atomicAdd(&cnt[dl], 1);
    }
    __syncthreads();
    int myc = cnt[t];
    tscan[t] = myc;
    __syncthreads();
    for (int off = 1; off < 256; off <<= 1) {
        int u = (t >= off) ? tscan[t - off] : 0;
        __syncthreads();
        tscan[t] += u;
        __syncthreads();
    }
    rowst[t] = tscan[t] - myc;
    place[t] = tscan[t] - myc;
    __syncthreads();
    for (int i = t; i < nEb; i += 256) {
        uint pk = eb[i];
        int dl = (int)(pk >> 16) - nbase;
        int slot = atomicAdd(&place[dl], 1);
        ssrc[slot] = (ushort)(pk & 0xffffu);
    }
    __syncthreads();
    int n = nbase + t;
    if (t < BIN_NODES && n < N_NODES) {
        int rs = rowst[t];
        fillpos[n] = myc;
        int dmax = min(myc, CAP);
        for (int p = 0; p < dmax; ++p)
            col2[(size_t)p * N_NODES + n] = ssrc[rs + p];
    }
}

// fp8 gather accumulate: uint2 = 8 fp8 e4m3 values
#define ACC8F8(A, V) \
    A[0] += __builtin_amdgcn_cvt_f32_fp8(V.x, 0); A[1] += __builtin_amdgcn_cvt_f32_fp8(V.x, 1); \
    A[2] += __builtin_amdgcn_cvt_f32_fp8(V.x, 2); A[3] += __builtin_amdgcn_cvt_f32_fp8(V.x, 3); \
    A[4] += __builtin_amdgcn_cvt_f32_fp8(V.y, 0); A[5] += __builtin_amdgcn_cvt_f32_fp8(V.y, 1); \
    A[6] += __builtin_amdgcn_cvt_f32_fp8(V.y, 2); A[7] += __builtin_amdgcn_cvt_f32_fp8(V.y, 3);

// uint4 = 16 fp8 e4m3 values
#define ACC16F8(A, V) \
    A[0]  += __builtin_amdgcn_cvt_f32_fp8(V.x, 0); A[1]  += __builtin_amdgcn_cvt_f32_fp8(V.x, 1); \
    A[2]  += __builtin_amdgcn_cvt_f32_fp8(V.x, 2); A[3]  += __builtin_amdgcn_cvt_f32_fp8(V.x, 3); \
    A[4]  += __builtin_amdgcn_cvt_f32_fp8(V.y, 0); A[5]  += __builtin_amdgcn_cvt_f32_fp8(V.y, 1); \
    A[6]  += __builtin_amdgcn_cvt_f32_fp8(V.y, 2); A[7]  += __builtin_amdgcn_cvt_f32_fp8(V.y, 3); \
    A[8]  += __builtin_amdgcn_cvt_f32_fp8(V.z, 0); A[9]  += __builtin_amdgcn_cvt_f32_fp8(V.z, 1); \
    A[10] += __builtin_amdgcn_cvt_f32_fp8(V.z, 2); A[11] += __builtin_amdgcn_cvt_f32_fp8(V.z, 3); \
    A[12] += __builtin_amdgcn_cvt_f32_fp8(V.w, 0); A[13] += __builtin_amdgcn_cvt_f32_fp8(V.w, 1); \
    A[14] += __builtin_amdgcn_cvt_f32_fp8(V.w, 2); A[15] += __builtin_amdgcn_cvt_f32_fp8(V.w, 3);

// ---------------- mean aggregation layer 1 ----------
// ONE NODE PER 8-LANE GROUP: lane owns 16B of the 128B fp8 row; 4x unrolled walk.

__global__ __launch_bounds__(256) void agg128_kernel(const uchar* __restrict__ xf8,
                                                     const int* __restrict__ fillpos,
                                                     const ushort* __restrict__ col2,
                                                     ushort* __restrict__ aggb) {
    const int t = threadIdx.x;
    const int n = blockIdx.x * 32 + (t >> 3);
    const int lr = t & 7;
    if (n >= N_NODES) return;
    int deg = fillpos[n];
    if (deg > CAP) deg = CAP;
    float a[16] = {}, b[16] = {};
    int j = 0;
    for (; j + 3 < deg; j += 4) {
        int c0 = col2[(size_t)j * N_NODES + n];
        int c1 = col2[(size_t)(j + 1) * N_NODES + n];
        int c2 = col2[(size_t)(j + 2) * N_NODES + n];
        int c3 = col2[(size_t)(j + 3) * N_NODES + n];
        uint4 v0 = *reinterpret_cast<const uint4*>(xf8 + (size_t)c0 * F_IN + lr * 16);
        uint4 v1 = *reinterpret_cast<const uint4*>(xf8 + (size_t)c1 * F_IN + lr * 16);
        uint4 v2 = *reinterpret_cast<const uint4*>(xf8 + (size_t)c2 * F_IN + lr * 16);
        uint4 v3 = *reinterpret_cast<const uint4*>(xf8 + (size_t)c3 * F_IN + lr * 16);
        ACC16F8(a, v0) ACC16F8(b, v1) ACC16F8(a, v2) ACC16F8(b, v3)
    }
    for (; j < deg; ++j) {
        int c = col2[(size_t)j * N_NODES + n];
        uint4 v = *reinterpret_cast<const uint4*>(xf8 + (size_t)c * F_IN + lr * 16);
        ACC16F8(a, v)
    }
    float inv = 1.0f / (float)max(deg, 1);
    uint4 o0, o1;
    o0.x = (uint)f2bf((a[0]  + b[0])  * inv) | ((uint)f2bf((a[1]  + b[1])  * inv) << 16);
    o0.y = (uint)f2bf((a[2]  + b[2])  * inv) | ((uint)f2bf((a[3]  + b[3])  * inv) << 16);
    o0.z = (uint)f2bf((a[4]  + b[4])  * inv) | ((uint)f2bf((a[5]  + b[5])  * inv) << 16);
    o0.w = (uint)f2bf((a[6]  + b[6])  * inv) | ((uint)f2bf((a[7]  + b[7])  * inv) << 16);
    o1.x = (uint)f2bf((a[8]  + b[8])  * inv) | ((uint)f2bf((a[9]  + b[9])  * inv) << 16);
    o1.y = (uint)f2bf((a[10] + b[10]) * inv) | ((uint)f2bf((a[11] + b[11]) * inv) << 16);
    o1.z = (uint)f2bf((a[12] + b[12]) * inv) | ((uint)f2bf((a[13] + b[13]) * inv) << 16);
    o1.w = (uint)f2bf((a[14] + b[14]) * inv) | ((uint)f2bf((a[15] + b[15]) * inv) << 16);
    *reinterpret_cast<uint4*>(aggb + (size_t)n * F_IN + lr * 16) = o0;
    *reinterpret_cast<uint4*>(aggb + (size_t)n * F_IN + lr * 16 + 8) = o1;
}

// ---------------- fused GEMM1+GEMM2, 64-row tiles (high occupancy) ----------------
// LDS 32KB: B1-quarter staging (64 cols x 256 k), then per-wave 8KB h-stage overlay.
// A-frags hoisted to regs; h never touches global.

__global__ __launch_bounds__(256, 4) void gemm12_kernel(const ushort* __restrict__ aggb,
                                                        const ushort* __restrict__ xb,
                                                        const ushort* __restrict__ Wb1,
                                                        const float* __restrict__ b1,
                                                        const ushort* __restrict__ Wb2,
                                                        const float* __restrict__ b2,
                                                        uchar* __restrict__ hWf8,
                                                        ushort* __restrict__ selfb) {
    __shared__ __align__(16) char S[32768];
    const int t = threadIdx.x, w = t >> 6, l = t & 63;
    const int bm = blockIdx.x * 64;
    const int lr = l & 15, lg = l >> 4;
    const int lrow = w * 16 + lr;

    bf16x8 aa[4], ax[4];
#pragma unroll
    for (int kk = 0; kk < 4; ++kk) {
        aa[kk] = *reinterpret_cast<const bf16x8*>(aggb + (size_t)(bm + lrow) * F_IN + kk * 32 + lg * 8);
        ax[kk] = *reinterpret_cast<const bf16x8*>(xb + (size_t)(bm + lrow) * F_IN + kk * 32 + lg * 8);
    }
    f32x4 acc[16] = {};
#pragma unroll
    for (int q = 0; q < 4; ++q) {
        for (int i = t; i < 64 * 32; i += 256) {
            int nn = i >> 5, k8 = (i & 31) * 8;
            uint4 v = *reinterpret_cast<const uint4*>(Wb1 + (size_t)(q * 64 + nn) * 256 + k8);
            *reinterpret_cast<uint4*>(S + ((nn * 512 + k8 * 2) ^ ((nn & 7) << 4))) = v;
        }
        __syncthreads();
#pragma unroll
        for (int kt = 0; kt < 8; ++kt) {
            bf16x8 af = (kt < 4) ? aa[kt & 3] : ax[kt & 3];
            int kbyte = kt * 64 + lg * 16;
#pragma unroll
            for (int jl = 0; jl < 4; ++jl) {
                int lc = jl * 16 + lr;
                bf16x8 bf = *reinterpret_cast<const bf16x8*>(S + ((lc * 512 + kbyte) ^ ((lc & 7) << 4)));
                acc[q * 4 + jl] = __builtin_amdgcn_mfma_f32_16x16x32_bf16(af, bf, acc[q * 4 + jl], 0, 0, 0);
            }
        }
        __syncthreads();
    }

    // h epilogue -> per-wave 8KB h-stage (16 rows x 512B, swizzled)
#pragma unroll
    for (int jj = 0; jj < 16; ++jj) {
        int c = jj * 16 + lr;
        float bias = b1[c];
#pragma unroll
        for (int r = 0; r < 4; ++r) {
            float v = fmaxf(acc[jj][r] + bias, 0.f);
            int rrow = lg * 4 + r;              // 0..15 local
            *reinterpret_cast<ushort*>(
                S + w * 8192 + ((rrow * 512 + c * 2) ^ ((rrow & 7) << 4))) = f2bf(v);
        }
    }
    __syncthreads();

    // GEMM2: A from own h-stage, B = Wb2 from global (L2)
    f32x4 acc2[5] = {};
#pragma unroll
    for (int kt = 0; kt < 8; ++kt) {
        int kbyte = kt * 64 + lg * 16;
        bf16x8 af = *reinterpret_cast<const bf16x8*>(
            S + w * 8192 + ((lr * 512 + kbyte) ^ ((lr & 7) << 4)));
#pragma unroll
        for (int j5 = 0; j5 < 5; ++j5) {
            int nl = j5 * 16 + lr;
            bf16x8 bf = *reinterpret_cast<const bf16x8*>(Wb2 + (size_t)nl * 256 + kt * 32 + lg * 8);
            acc2[j5] = __builtin_amdgcn_mfma_f32_16x16x32_bf16(af, bf, acc2[j5], 0, 0, 0);
        }
    }
#pragma unroll
    for (int j5 = 0; j5 < 5; ++j5) {
        int cfull = j5 * 16 + lr;
#pragma unroll
        for (int r = 0; r < 4; ++r) {
            int row = bm + w * 16 + lg * 4 + r;
            float v = acc2[j5][r];
            if (cfull < 40) {
                hWf8[(size_t)row * 64 + cfull] = f2fp8(v);        // 64B (1-line) rows
            } else {
                int c = cfull - 40;
                selfb[(size_t)row * 40 + c] = f2bf(v + b2[c]);
            }
        }
    }
}

// ---------------- fused: out = log_softmax(self + mean_j hW_j) ----------------
// ONE NODE PER 8-LANE GROUP: lanes lr<5 own 8 classes each across ALL edges
// (no cross-group combine); 4x unrolled walk -> 4 gathers in flight per group.

__global__ __launch_bounds__(256) void agg40_lsm_kernel(const uchar* __restrict__ hWf8,
                                                        const ushort* __restrict__ selfb,
                                                        const int* __restrict__ fillpos,
                                                        const ushort* __restrict__ col2,
                                                        float* __restrict__ out) {
    const int t = threadIdx.x;
    const int n = blockIdx.x * 32 + (t >> 3);
    const int lr = t & 7;
    if (n >= N_NODES) return;
    const bool act = lr < 5;
    int deg = fillpos[n];
    if (deg > CAP) deg = CAP;
    // self part issued early (hides under gather chain)
    uint4 sv = {};
    if (act) sv = *reinterpret_cast<const uint4*>(selfb + (size_t)n * 40 + lr * 8);
    float a[8] = {}, b[8] = {};
    int j = 0;
    for (; j + 3 < deg; j += 4) {
        int c0 = col2[(size_t)j * N_NODES + n];
        int c1 = col2[(size_t)(j + 1) * N_NODES + n];
        int c2 = col2[(size_t)(j + 2) * N_NODES + n];
        int c3 = col2[(size_t)(j + 3) * N_NODES + n];
        if (act) {
            uint2 v0 = *reinterpret_cast<const uint2*>(hWf8 + (size_t)c0 * 64 + lr * 8);
            uint2 v1 = *reinterpret_cast<const uint2*>(hWf8 + (size_t)c1 * 64 + lr * 8);
            uint2 v2 = *reinterpret_cast<const uint2*>(hWf8 + (size_t)c2 * 64 + lr * 8);
            uint2 v3 = *reinterpret_cast<const uint2*>(hWf8 + (size_t)c3 * 64 + lr * 8);
            ACC8F8(a, v0) ACC8F8(b, v1) ACC8F8(a, v2) ACC8F8(b, v3)
        }
    }
    for (; j < deg; ++j) {
        int c = col2[(size_t)j * N_NODES + n];
        if (act) {
            uint2 v = *reinterpret_cast<const uint2*>(hWf8 + (size_t)c * 64 + lr * 8);
            ACC8F8(a, v)
        }
    }
    float inv = 1.0f / (float)max(deg, 1);
    float v[8];
    if (act) {
        v[0] = bf2f(sv.x & 0xffffu) + (a[0] + b[0]) * inv;
        v[1] = bf2f(sv.x >> 16)     + (a[1] + b[1]) * inv;
        v[2] = bf2f(sv.y & 0xffffu) + (a[2] + b[2]) * inv;
        v[3] = bf2f(sv.y >> 16)     + (a[3] + b[3]) * inv;
        v[4] = bf2f(sv.z & 0xffffu) + (a[4] + b[4]) * inv;
        v[5] = bf2f(sv.z >> 16)     + (a[5] + b[5]) * inv;
        v[6] = bf2f(sv.w & 0xffffu) + (a[6] + b[6]) * inv;
        v[7] = bf2f(sv.w >> 16)     + (a[7] + b[7]) * inv;
    } else {
#pragma unroll
        for (int i = 0; i < 8; ++i) v[i] = -INFINITY;
    }
    float m = v[0];
#pragma unroll
    for (int i = 1; i < 8; ++i) m = fmaxf(m, v[i]);
    m = fmaxf(m, __shfl_xor(m, 1));
    m = fmaxf(m, __shfl_xor(m, 2));
    m = fmaxf(m, __shfl_xor(m, 4));
    float ex = 0.f;
    if (act) {
#pragma unroll
        for (int i = 0; i < 8; ++i) ex += expf(v[i] - m);
    }
    ex += __shfl_xor(ex, 1);
    ex += __shfl_xor(ex, 2);
    ex += __shfl_xor(ex, 4);
    float ls = logf(ex);
    if (act) {
        float* ob = out + (size_t)n * NCLS + lr * 8;
        float4 o0, o1;
        o0.x = v[0] - m - ls; o0.y = v[1] - m - ls; o0.z = v[2] - m - ls; o0.w = v[3] - m - ls;
        o1.x = v[4] - m - ls; o1.y = v[5] - m - ls; o1.z = v[6] - m - ls; o1.w = v[7] - m - ls;
        *reinterpret_cast<float4*>(ob) = o0;
        *reinterpret_cast<float4*>(ob + 4) = o1;
    }
}

// ---------------- launch ----------------

static inline size_t align256(size_t x) { return (x + 255) & ~(size_t)255; }

extern "C" void kernel_launch(void* const* d_in, const int* in_sizes, int n_in,
                              void* d_out, int out_size, void* d_ws, size_t ws_size,
                              hipStream_t stream) {
    const float* x    = (const float*)d_in[0];
    const int*   ei   = (const int*)d_in[1];
    const float* W1l  = (const float*)d_in[2];
    const float* b1   = (const float*)d_in[3];
    const float* W1r  = (const float*)d_in[4];
    const float* W2l  = (const float*)d_in[5];
    const float* b2   = (const float*)d_in[6];
    const float* W2r  = (const float*)d_in[7];
    float* out = (float*)d_out;

    const int N = N_NODES;
    const int E = in_sizes[1] / 2;
    const int* srcArr = ei;
    const int* dstArr = ei + E;

    char* ws = (char*)d_ws;
    size_t off = 0;
    auto alloc = [&](size_t bytes) { size_t o = off; off = align256(off + bytes); return o; };
    int*    fillpos  = (int*)(ws + alloc((size_t)N * 4));
    int*    bin_cnt  = (int*)(ws + alloc((size_t)NBIN * 4));
    uint*   binbuf   = (uint*)(ws + alloc((size_t)NBIN * BSTRIDE * 4));   // 4 MB
    ushort* col2     = (ushort*)(ws + alloc((size_t)CAP * N * 2));        // layer-major
    ushort* xb       = (ushort*)(ws + alloc((size_t)NPAD * F_IN * 2));
    uchar*  xf8      = (uchar*)(ws + alloc((size_t)NPAD * F_IN));
    ushort* aggb     = (ushort*)(ws + alloc((size_t)NPAD * F_IN * 2));
    uchar*  hWf8     = (uchar*)(ws + alloc((size_t)NPAD * 64));
    ushort* selfb    = (ushort*)(ws + alloc((size_t)NPAD * 40 * 2));
    ushort* Wb1      = (ushort*)(ws + alloc((size_t)256 * 256 * 2));
    ushort* Wb2      = (ushort*)(ws + alloc((size_t)80 * 256 * 2));
    (void)ws_size; (void)n_in; (void)out_size;

    // 1. prep: cast (bf16 + fp8) + pack + zero bin counters
    prep_kernel<<<6587, 256, 0, stream>>>(x, xb, xf8, W1l, W1r, W2l, W2r, Wb1, Wb2, bin_cnt);
    // 2. pass A: bin edges into 256 node-range bins
    bin_kernel<<<(E + 2047) / 2048, 256, 0, stream>>>(srcArr, dstArr, bin_cnt, binbuf, E);
    // 3. pass B: per-bin counting sort -> dense col2 + fillpos
    fillb_kernel<<<NBIN, 256, 0, stream>>>(bin_cnt, binbuf, fillpos, col2);
    // 4. layer-1 mean aggregation (node-per-8-lane-group, 4-deep MLP)
    agg128_kernel<<<(N + 31) / 32, 256, 0, stream>>>(xf8, fillpos, col2, aggb);
    // 5. fused gemm1+gemm2, 64-row tiles (h stays in LDS)
    gemm12_kernel<<<NPAD / 64, 256, 0, stream>>>(aggb, xb, Wb1, b1, Wb2, b2, hWf8, selfb);
    // 6. layer-2 aggregation + self + log_softmax (node-per-8-lane-group)
    agg40_lsm_kernel<<<(N + 31) / 32, 256, 0, stream>>>(hWf8, selfb, fillpos, col2, out);
}